// Round 1
// baseline (357.576 us; speedup 1.0000x reference)
//
#include <hip/hip_runtime.h>
#include <stdint.h>

// ---------------------------------------------------------------------------
// DetectionHead: RoIAlign(1000 rois, 256ch, 7x7, SR=2) + 2-branch MLP.
// Strategy: everything matmul-shaped goes through bf16 MFMA 16x16x32
// (m97-style 128x128 tile, global_load_lds width=16, XOR-swizzled LDS).
// fp32 weights are transposed+converted to bf16 once per launch (prep).
// ---------------------------------------------------------------------------

#define AS1 __attribute__((address_space(1)))
#define AS3 __attribute__((address_space(3)))

typedef __attribute__((ext_vector_type(8))) short short8;    // 8 bf16 = 4 VGPRs
typedef __attribute__((ext_vector_type(4))) float float4v;   // MFMA C/D

#define D_FEAT 12544   // 49*256
#define MPAD   1024    // padded roi count (K=1000)

__device__ __forceinline__ uint16_t f2bf(float f) {
  union { float f; uint32_t u; } v; v.f = f;
  uint32_t r = v.u + 0x7FFFu + ((v.u >> 16) & 1u);   // RNE
  return (uint16_t)(r >> 16);
}
__device__ __forceinline__ float bf2f(uint16_t h) {
  union { uint32_t u; float f; } v; v.u = ((uint32_t)h) << 16;
  return v.f;
}

__device__ __forceinline__ void gll16(const void* g, void* l) {
  // async global->LDS, 16B per lane; LDS dest = uniform base + lane*16
  __builtin_amdgcn_global_load_lds((const AS1 uint32_t*)g, (AS3 uint32_t*)l, 16, 0, 0);
}

// ---------------------------------------------------------------------------
// prep: tiled transpose + fp32->bf16 convert (+ optional row permute / n-pad)
//   dst[n][k] = src[perm(k)][n], dst bf16 k-contiguous.
// Ranges (blockIdx.x):
//   [0,320)      features b0/b1: [256][2500] -> featT [2500][256]
//   [320,6592)   W1|Wc1: [12544][1024] -> w1t [2048][12544], rows permuted
//                so GEMM-k index k' = s*256+c maps to W row c*49+s
//   [6592,6848)  W2 -> w2t [1024][1024]
//   [6848,6880)  W3 [1024][4] -> w3t [128][1024] zero-padded
//   [6880,6912)  Wc2 [1024][81] -> wc2t [128][1024] zero-padded
// ---------------------------------------------------------------------------
__global__ __launch_bounds__(256) void prep_kernel(
    const float* __restrict__ features, const float* __restrict__ W1,
    const float* __restrict__ Wc1, const float* __restrict__ W2,
    const float* __restrict__ W3, const float* __restrict__ Wc2,
    uint16_t* __restrict__ featT, uint16_t* __restrict__ w1t,
    uint16_t* __restrict__ w2t, uint16_t* __restrict__ w3t,
    uint16_t* __restrict__ wc2t)
{
  __shared__ float tile[64][65];
  int b = blockIdx.x;
  const float* src; uint16_t* dst;
  int Csrc, Cpad, ldk, rowStride, rowBase, k0, n0;

  if (b < 320) {
    int img = (b >= 160); int bb = b - img * 160;
    int kt = bb & 3, nt = bb >> 2;
    src = features + (size_t)img * 256 * 2500;
    dst = featT + (size_t)img * 2500 * 256;
    Csrc = 2500; Cpad = 2500; ldk = 256; rowStride = 1;
    k0 = kt * 64; n0 = nt * 64; rowBase = k0;
  } else if (b < 6592) {
    int bb = b - 320; int which = (bb >= 3136); bb -= which * 3136;
    int kt = bb % 196, nt = bb / 196;
    src = which ? Wc1 : W1;
    dst = w1t + (size_t)(which ? 1024 : 0) * D_FEAT;
    Csrc = 1024; Cpad = 1024; ldk = D_FEAT;
    k0 = kt * 64; n0 = nt * 64;
    int s = k0 >> 8, c0 = k0 & 255;      // k' = s*256 + c
    rowBase = c0 * 49 + s; rowStride = 49;
  } else if (b < 6848) {
    int bb = b - 6592; int kt = bb & 15, nt = bb >> 4;
    src = W2; dst = w2t; Csrc = 1024; Cpad = 1024; ldk = 1024;
    rowStride = 1; k0 = kt * 64; n0 = nt * 64; rowBase = k0;
  } else if (b < 6880) {
    int bb = b - 6848; int kt = bb & 15, nt = bb >> 4;
    src = W3; dst = w3t; Csrc = 4; Cpad = 128; ldk = 1024;
    rowStride = 1; k0 = kt * 64; n0 = nt * 64; rowBase = k0;
  } else {
    int bb = b - 6880; int kt = bb & 15, nt = bb >> 4;
    src = Wc2; dst = wc2t; Csrc = 81; Cpad = 128; ldk = 1024;
    rowStride = 1; k0 = kt * 64; n0 = nt * 64; rowBase = k0;
  }

  int t = threadIdx.x; int cl = t & 63; int r4 = t >> 6;
#pragma unroll
  for (int i = 0; i < 16; i++) {
    int kl = r4 + i * 4;
    int n = n0 + cl;
    float v = 0.f;
    if (n < Csrc) v = src[(size_t)(rowBase + kl * rowStride) * Csrc + n];
    tile[kl][cl] = v;
  }
  __syncthreads();
#pragma unroll
  for (int i = 0; i < 16; i++) {
    int nl = r4 + i * 4; int n = n0 + nl;
    if (n < Cpad) dst[(size_t)n * ldk + k0 + (t & 63)] = f2bf(tile[t & 63][nl]);
  }
}

// ---------------------------------------------------------------------------
// RoIAlign: block per (padded) roi, lane per channel. featT is NHWC bf16 so
// the 256 channels of one tap are 512B contiguous (coalesced).
// Output layout: xb[roi][ (py*7+px)*256 + c ]  (bin-major; w1t rows permuted
// to match). Rows >= K zeroed (GEMM M padded to 1024).
// ---------------------------------------------------------------------------
__global__ __launch_bounds__(256) void roialign_kernel(
    const uint16_t* __restrict__ featT, const float* __restrict__ props,
    uint16_t* __restrict__ xb, int K)
{
  __shared__ float wy0[14], wy1[14], wx0[14], wx1[14];
  __shared__ int iy0[14], iy1[14], ix0[14], ix1[14];
  __shared__ int sb;
  int roi = blockIdx.x;
  int c = threadIdx.x;
  if (roi >= K) {
    uint16_t* xr = xb + (size_t)roi * D_FEAT + c;
    for (int s = 0; s < 49; s++) xr[s * 256] = 0;
    return;
  }
  if (threadIdx.x < 28) {
    int j = threadIdx.x % 14;
    bool isx = threadIdx.x >= 14;
    const float* p = props + roi * 5;
    float lo = (isx ? p[1] : p[2]) * 0.0625f;
    float hi = (isx ? p[3] : p[4]) * 0.0625f;
    float ext = fmaxf(hi - lo, 1.0f);
    float bin = ext * (1.0f / 7.0f);
    float y = lo + (j + 0.5f) * 0.5f * bin;     // t = (j+0.5)/2 in bin units
    bool valid = (y > -1.0f) && (y < 50.0f);
    float yc = fminf(fmaxf(y, 0.0f), 49.0f);
    int i0 = (int)yc;                            // yc>=0 -> trunc==floor
    int i1 = min(i0 + 1, 49);
    float fhi = yc - (float)i0;
    float flo = 1.0f - fhi;
    if (!valid) { flo = 0.0f; fhi = 0.0f; }
    if (isx) { ix0[j] = i0; ix1[j] = i1; wx0[j] = flo; wx1[j] = fhi; }
    else     { iy0[j] = i0; iy1[j] = i1; wy0[j] = flo; wy1[j] = fhi; }
  }
  if (threadIdx.x == 0) sb = (int)props[roi * 5];
  __syncthreads();

  const uint16_t* fb = featT + (size_t)sb * (2500 * 256) + c;
  uint16_t* xr = xb + (size_t)roi * D_FEAT + c;
  for (int py = 0; py < 7; py++) {
    for (int px = 0; px < 7; px++) {
      float acc = 0.f;
#pragma unroll
      for (int sy = 0; sy < 2; sy++) {
        int jy = py * 2 + sy;
        int y0 = iy0[jy], y1 = iy1[jy];
        float a0 = wy0[jy], a1 = wy1[jy];
#pragma unroll
        for (int sx = 0; sx < 2; sx++) {
          int jx = px * 2 + sx;
          int x0 = ix0[jx], x1 = ix1[jx];
          float b0 = wx0[jx], b1 = wx1[jx];
          float v00 = bf2f(fb[(y0 * 50 + x0) * 256]);
          float v01 = bf2f(fb[(y0 * 50 + x1) * 256]);
          float v10 = bf2f(fb[(y1 * 50 + x0) * 256]);
          float v11 = bf2f(fb[(y1 * 50 + x1) * 256]);
          acc += a0 * (b0 * v00 + b1 * v01) + a1 * (b0 * v10 + b1 * v11);
        }
      }
      xr[(py * 7 + px) * 256] = f2bf(acc * 0.25f);
    }
  }
}

// ---------------------------------------------------------------------------
// GEMM core: C[128x128] tile, BK=32, 256 threads (4 waves, 64x64 each).
// Both operands stored [row][k] k-contiguous; staged via global_load_lds
// width-16 with an XOR swizzle so frag ds_read_b128 is 2-way max (free).
// LDS slot layout: addr(m,kg) = m*32 + (kg ^ ((m>>1)&3))*8   (ushort units)
// ---------------------------------------------------------------------------
__device__ __forceinline__ void gemm_core(
    const uint16_t* __restrict__ A, int lda,
    const uint16_t* __restrict__ BT, int ldb,
    int Mbase, int Nbase, int kStart, int kSteps,
    uint16_t* As, uint16_t* Bs, float4v acc[4][4])
{
  const int t = threadIdx.x;
  const int w = t >> 6, L = t & 63;
  const int wm = (w & 1) * 64, wn = (w >> 1) * 64;

  // staging: wave w loads rows [32w, 32w+32) of each tile (2 instrs each)
  const int kg = (L & 3) ^ ((L >> 3) & 3);   // XOR swizzle on k-group
  const int rsub = L >> 2;
  const uint16_t* aG0 = A + (size_t)(Mbase + 32 * w + rsub) * lda + kStart + kg * 8;
  const uint16_t* aG1 = aG0 + (size_t)16 * lda;
  const uint16_t* bG0 = BT + (size_t)(Nbase + 32 * w + rsub) * ldb + kStart + kg * 8;
  const uint16_t* bG1 = bG0 + (size_t)16 * ldb;
  uint16_t* aL0 = As + (2 * w) * 512;  uint16_t* aL1 = aL0 + 512;
  uint16_t* bL0 = Bs + (2 * w) * 512;  uint16_t* bL1 = bL0 + 512;

  // fragment read addresses (swizzle-corrected, lane-constant offset)
  const int q = L >> 4, lr = L & 15;
  const int slot = q ^ ((L >> 1) & 3);
  const uint16_t* aF = As + (wm + lr) * 32 + slot * 8;
  const uint16_t* bF = Bs + (wn + lr) * 32 + slot * 8;

  for (int ks = 0; ks < kSteps; ks++) {
    __syncthreads();                       // LDS free (drains prior reads)
    gll16(aG0, aL0); gll16(aG1, aL1);
    gll16(bG0, bL0); gll16(bG1, bL1);
    __syncthreads();                       // implicit s_waitcnt vmcnt(0)

    short8 a0 = *(const short8*)(aF);
    short8 a1 = *(const short8*)(aF + 512);
    short8 a2 = *(const short8*)(aF + 1024);
    short8 a3 = *(const short8*)(aF + 1536);
    short8 b0 = *(const short8*)(bF);
    short8 b1 = *(const short8*)(bF + 512);
    short8 b2 = *(const short8*)(bF + 1024);
    short8 b3 = *(const short8*)(bF + 1536);

    acc[0][0] = __builtin_amdgcn_mfma_f32_16x16x32_bf16(a0, b0, acc[0][0], 0, 0, 0);
    acc[0][1] = __builtin_amdgcn_mfma_f32_16x16x32_bf16(a0, b1, acc[0][1], 0, 0, 0);
    acc[0][2] = __builtin_amdgcn_mfma_f32_16x16x32_bf16(a0, b2, acc[0][2], 0, 0, 0);
    acc[0][3] = __builtin_amdgcn_mfma_f32_16x16x32_bf16(a0, b3, acc[0][3], 0, 0, 0);
    acc[1][0] = __builtin_amdgcn_mfma_f32_16x16x32_bf16(a1, b0, acc[1][0], 0, 0, 0);
    acc[1][1] = __builtin_amdgcn_mfma_f32_16x16x32_bf16(a1, b1, acc[1][1], 0, 0, 0);
    acc[1][2] = __builtin_amdgcn_mfma_f32_16x16x32_bf16(a1, b2, acc[1][2], 0, 0, 0);
    acc[1][3] = __builtin_amdgcn_mfma_f32_16x16x32_bf16(a1, b3, acc[1][3], 0, 0, 0);
    acc[2][0] = __builtin_amdgcn_mfma_f32_16x16x32_bf16(a2, b0, acc[2][0], 0, 0, 0);
    acc[2][1] = __builtin_amdgcn_mfma_f32_16x16x32_bf16(a2, b1, acc[2][1], 0, 0, 0);
    acc[2][2] = __builtin_amdgcn_mfma_f32_16x16x32_bf16(a2, b2, acc[2][2], 0, 0, 0);
    acc[2][3] = __builtin_amdgcn_mfma_f32_16x16x32_bf16(a2, b3, acc[2][3], 0, 0, 0);
    acc[3][0] = __builtin_amdgcn_mfma_f32_16x16x32_bf16(a3, b0, acc[3][0], 0, 0, 0);
    acc[3][1] = __builtin_amdgcn_mfma_f32_16x16x32_bf16(a3, b1, acc[3][1], 0, 0, 0);
    acc[3][2] = __builtin_amdgcn_mfma_f32_16x16x32_bf16(a3, b2, acc[3][2], 0, 0, 0);
    acc[3][3] = __builtin_amdgcn_mfma_f32_16x16x32_bf16(a3, b3, acc[3][3], 0, 0, 0);

    aG0 += 32; aG1 += 32; bG0 += 32; bG1 += 32;   // advance K by 32 elems
  }
}

// split-K partial GEMM: writes fp32 partial tile to P + z*zstride
__global__ __launch_bounds__(256) void gemm_partial_kernel(
    const uint16_t* __restrict__ A, int lda,
    const uint16_t* __restrict__ BT, int ldb,
    int kChunk, float* __restrict__ P, int ldc, size_t zstride)
{
  __shared__ __align__(16) uint16_t As[4096];
  __shared__ __align__(16) uint16_t Bs[4096];
  float4v acc[4][4];
  float4v zero = {0.f, 0.f, 0.f, 0.f};
#pragma unroll
  for (int i = 0; i < 4; i++)
#pragma unroll
    for (int j = 0; j < 4; j++) acc[i][j] = zero;

  gemm_core(A, lda, BT, ldb, blockIdx.x * 128, blockIdx.y * 128,
            blockIdx.z * kChunk, kChunk >> 5, As, Bs, acc);

  const int t = threadIdx.x, w = t >> 6, L = t & 63;
  const int wm = (w & 1) * 64, wn = (w >> 1) * 64, q = L >> 4, lr = L & 15;
  float* Pz = P + (size_t)blockIdx.z * zstride;
#pragma unroll
  for (int mi = 0; mi < 4; mi++)
#pragma unroll
    for (int ni = 0; ni < 4; ni++) {
      int row = blockIdx.x * 128 + wm + mi * 16 + q * 4;   // C: row=quad*4+reg
      int col = blockIdx.y * 128 + wn + ni * 16 + lr;      //    col=lane&15
      float* pp = Pz + (size_t)row * ldc + col;
      pp[0]           = acc[mi][ni][0];
      pp[ldc]         = acc[mi][ni][1];
      pp[2 * ldc]     = acc[mi][ni][2];
      pp[3 * ldc]     = acc[mi][ni][3];
    }
}

// sum split-K partials + bias + relu -> bf16
__global__ void reduce_kernel(
    const float* __restrict__ P, int nsplit, size_t zstride,
    const float* __restrict__ biasLo, const float* __restrict__ biasHi,
    int colSplit, int ldrow, uint16_t* __restrict__ out, int total4)
{
  int tid = blockIdx.x * blockDim.x + threadIdx.x;
  if (tid >= total4) return;
  size_t i4 = (size_t)tid * 4;
  int col = (int)(i4 % (size_t)ldrow);
  float4 s = *(const float4*)(P + i4);
  for (int z = 1; z < nsplit; z++) {
    float4 p = *(const float4*)(P + (size_t)z * zstride + i4);
    s.x += p.x; s.y += p.y; s.z += p.z; s.w += p.w;
  }
  const float* bp = (col < colSplit) ? (biasLo + col) : (biasHi + (col - colSplit));
  s.x = fmaxf(s.x + bp[0], 0.f);
  s.y = fmaxf(s.y + bp[1], 0.f);
  s.z = fmaxf(s.z + bp[2], 0.f);
  s.w = fmaxf(s.w + bp[3], 0.f);
  uint32_t lo = (uint32_t)f2bf(s.x) | ((uint32_t)f2bf(s.y) << 16);
  uint32_t hi = (uint32_t)f2bf(s.z) | ((uint32_t)f2bf(s.w) << 16);
  *(uint2*)(out + i4) = make_uint2(lo, hi);
}

// final layers: y=0: bbox = hb2 @ W3 + b3 ; y=1: logits = cc @ Wc2 + bc2
__global__ __launch_bounds__(256) void gemm_final_kernel(
    const uint16_t* __restrict__ hb2, const uint16_t* __restrict__ cc,
    const uint16_t* __restrict__ w3t, const uint16_t* __restrict__ wc2t,
    const float* __restrict__ b3, const float* __restrict__ bc2,
    float* __restrict__ out, int K)
{
  __shared__ __align__(16) uint16_t As[4096];
  __shared__ __align__(16) uint16_t Bs[4096];
  float4v acc[4][4];
  float4v zero = {0.f, 0.f, 0.f, 0.f};
#pragma unroll
  for (int i = 0; i < 4; i++)
#pragma unroll
    for (int j = 0; j < 4; j++) acc[i][j] = zero;

  int which = blockIdx.y;
  const uint16_t* A = which ? cc : hb2;
  int lda = which ? 2048 : 1024;
  const uint16_t* BT = which ? wc2t : w3t;
  const float* bias = which ? bc2 : b3;
  int Ncols = which ? 81 : 4;
  float* ob = which ? (out + 4000) : out;
  int ldo = which ? 81 : 4;

  gemm_core(A, lda, BT, 1024, blockIdx.x * 128, 0, 0, 32, As, Bs, acc);

  const int t = threadIdx.x, w = t >> 6, L = t & 63;
  const int wm = (w & 1) * 64, wn = (w >> 1) * 64, q = L >> 4, lr = L & 15;
#pragma unroll
  for (int mi = 0; mi < 4; mi++)
#pragma unroll
    for (int ni = 0; ni < 4; ni++) {
      int col = wn + ni * 16 + lr;
      if (col < Ncols) {
        float bv = bias[col];
        int row0 = blockIdx.x * 128 + wm + mi * 16 + q * 4;
#pragma unroll
        for (int r = 0; r < 4; r++) {
          int row = row0 + r;
          if (row < K) ob[(size_t)row * ldo + col] = acc[mi][ni][r] + bv;
        }
      }
    }
}

// ---------------------------------------------------------------------------
extern "C" void kernel_launch(void* const* d_in, const int* in_sizes, int n_in,
                              void* d_out, int out_size, void* d_ws, size_t ws_size,
                              hipStream_t stream)
{
  const float* features = (const float*)d_in[0];
  const float* props    = (const float*)d_in[1];
  const float* W1  = (const float*)d_in[2];
  const float* b1  = (const float*)d_in[3];
  const float* W2  = (const float*)d_in[4];
  const float* b2  = (const float*)d_in[5];
  const float* W3  = (const float*)d_in[6];
  const float* b3  = (const float*)d_in[7];
  const float* Wc1 = (const float*)d_in[8];
  const float* bc1 = (const float*)d_in[9];
  const float* Wc2 = (const float*)d_in[10];
  const float* bc2 = (const float*)d_in[11];
  int K = in_sizes[1] / 5;   // 1000

  // workspace layout (bytes), ~122.1 MB total
  char* ws = (char*)d_ws;
  uint16_t* featT = (uint16_t*)(ws);               // 2,560,000   NHWC bf16
  uint16_t* xb    = (uint16_t*)(ws + 2560000);     // 25,690,112  A [1024][12544]
  uint16_t* w1t   = (uint16_t*)(ws + 28250112);    // 51,380,224  [W1|Wc1]^T [2048][12544]
  uint16_t* w2t   = (uint16_t*)(ws + 79630336);    // 2,097,152   W2^T [1024][1024]
  uint16_t* w3t   = (uint16_t*)(ws + 81727488);    // 262,144     W3^T [128][1024] pad
  uint16_t* wc2t  = (uint16_t*)(ws + 81989632);    // 262,144     Wc2^T [128][1024] pad
  float*    P     = (float*)   (ws + 82251776);    // 33,554,432  split-K partials
  uint16_t* hbcc  = (uint16_t*)(ws + 115806208);   // 4,194,304   [h|c] [1024][2048]
  uint16_t* hb2   = (uint16_t*)(ws + 120000512);   // 2,097,152   [1024][1024]

  prep_kernel<<<6912, 256, 0, stream>>>(features, W1, Wc1, W2, W3, Wc2,
                                        featT, w1t, w2t, w3t, wc2t);
  roialign_kernel<<<MPAD, 256, 0, stream>>>(featT, props, xb, K);
  // big GEMM: M=1024 N=2048 K=12544, split-K=4 -> 512 blocks
  gemm_partial_kernel<<<dim3(8, 16, 4), 256, 0, stream>>>(
      xb, D_FEAT, w1t, D_FEAT, 3136, P, 2048, (size_t)1024 * 2048);
  reduce_kernel<<<2048, 256, 0, stream>>>(P, 4, (size_t)1024 * 2048,
                                          b1, bc1, 1024, 2048, hbcc, 524288);
  // h @ W2: M=1024 N=1024 K=1024
  gemm_partial_kernel<<<dim3(8, 8, 1), 256, 0, stream>>>(
      hbcc, 2048, w2t, 1024, 1024, P, 1024, 0);
  reduce_kernel<<<1024, 256, 0, stream>>>(P, 1, 0, b2, b2, 1024, 1024, hb2, 262144);
  // final: bbox (hb2@W3+b3) and logits (cc@Wc2+bc2)
  gemm_final_kernel<<<dim3(8, 2), 256, 0, stream>>>(
      hb2, hbcc + 1024, w3t, wc2t, b3, bc2, (float*)d_out, K);
}

// Round 2
// 308.152 us; speedup vs baseline: 1.1604x; 1.1604x over previous
//
#include <hip/hip_runtime.h>
#include <stdint.h>

// ---------------------------------------------------------------------------
// DetectionHead: RoIAlign(1000 rois, 256ch, 7x7, SR=2) + 2-branch MLP.
// R2: gemm1 split-K=8 with XCD-swizzled 1D grid (z = L%8 -> each XCD owns one
// K-chunk, L2-shared B slices); vectorized prep (float4 loads, 16B stores);
// gemm2 split-K=8; final layer split-K=4 + reduce3.
// ---------------------------------------------------------------------------

#define AS1 __attribute__((address_space(1)))
#define AS3 __attribute__((address_space(3)))

typedef __attribute__((ext_vector_type(8))) short short8;    // 8 bf16 = 4 VGPRs
typedef __attribute__((ext_vector_type(4))) float float4v;   // MFMA C/D

#define D_FEAT 12544   // 49*256
#define MPAD   1024    // padded roi count (K=1000)

__device__ __forceinline__ uint16_t f2bf(float f) {
  union { float f; uint32_t u; } v; v.f = f;
  uint32_t r = v.u + 0x7FFFu + ((v.u >> 16) & 1u);   // RNE
  return (uint16_t)(r >> 16);
}
__device__ __forceinline__ float bf2f(uint16_t h) {
  union { uint32_t u; float f; } v; v.u = ((uint32_t)h) << 16;
  return v.f;
}

__device__ __forceinline__ void gll16(const void* g, void* l) {
  // async global->LDS, 16B per lane; LDS dest = uniform base + lane*16
  __builtin_amdgcn_global_load_lds((const AS1 uint32_t*)g, (AS3 uint32_t*)l, 16, 0, 0);
}

// ---------------------------------------------------------------------------
// prep: tiled transpose + fp32->bf16 convert. dst[n][k] = src[perm(k)][n].
// Vectorized: float4 loads, register 4x4 transpose, bf16 LDS, 16B stores.
// Block ranges as in R1 (6912 blocks total).
// ---------------------------------------------------------------------------
__global__ __launch_bounds__(256) void prep_kernel(
    const float* __restrict__ features, const float* __restrict__ W1,
    const float* __restrict__ Wc1, const float* __restrict__ W2,
    const float* __restrict__ W3, const float* __restrict__ Wc2,
    uint16_t* __restrict__ featT, uint16_t* __restrict__ w1t,
    uint16_t* __restrict__ w2t, uint16_t* __restrict__ w3t,
    uint16_t* __restrict__ wc2t)
{
  __shared__ __align__(16) uint16_t T[64][72];   // [n][k], 144B row = 9x16B
  int b = blockIdx.x;
  const float* src; uint16_t* dst;
  int Csrc, Cpad, ldk, rowStride, rowBase, k0, n0;

  if (b < 320) {
    int img = (b >= 160); int bb = b - img * 160;
    int kt = bb & 3, nt = bb >> 2;
    src = features + (size_t)img * 256 * 2500;
    dst = featT + (size_t)img * 2500 * 256;
    Csrc = 2500; Cpad = 2500; ldk = 256; rowStride = 1;
    k0 = kt * 64; n0 = nt * 64; rowBase = k0;
  } else if (b < 6592) {
    int bb = b - 320; int which = (bb >= 3136); bb -= which * 3136;
    int kt = bb % 196, nt = bb / 196;
    src = which ? Wc1 : W1;
    dst = w1t + (size_t)(which ? 1024 : 0) * D_FEAT;
    Csrc = 1024; Cpad = 1024; ldk = D_FEAT;
    k0 = kt * 64; n0 = nt * 64;
    int s = k0 >> 8, c0 = k0 & 255;      // gemm-k k' = s*256 + c -> W row c*49+s
    rowBase = c0 * 49 + s; rowStride = 49;
  } else if (b < 6848) {
    int bb = b - 6592; int kt = bb & 15, nt = bb >> 4;
    src = W2; dst = w2t; Csrc = 1024; Cpad = 1024; ldk = 1024;
    rowStride = 1; k0 = kt * 64; n0 = nt * 64; rowBase = k0;
  } else if (b < 6880) {
    int bb = b - 6848; int kt = bb & 15, nt = bb >> 4;
    src = W3; dst = w3t; Csrc = 4; Cpad = 128; ldk = 1024;
    rowStride = 1; k0 = kt * 64; n0 = nt * 64; rowBase = k0;
  } else {
    int bb = b - 6880; int kt = bb & 15, nt = bb >> 4;
    src = Wc2; dst = wc2t; Csrc = 81; Cpad = 128; ldk = 1024;
    rowStride = 1; k0 = kt * 64; n0 = nt * 64; rowBase = k0;
  }

  int t = threadIdx.x;
  int cb = (t & 15) * 4;        // n within tile
  int kb = (t >> 4) * 4;        // k within tile
  float v[4][4];
  if ((Csrc & 3) == 0) {
    int n = n0 + cb;
#pragma unroll
    for (int i = 0; i < 4; i++) {
      if (n < Csrc) {   // Csrc%4==0 -> whole float4 in-bounds iff n<Csrc
        const float* p = src + (size_t)(rowBase + (kb + i) * rowStride) * Csrc + n;
        float4 f = *(const float4*)p;
        v[i][0] = f.x; v[i][1] = f.y; v[i][2] = f.z; v[i][3] = f.w;
      } else {
        v[i][0] = v[i][1] = v[i][2] = v[i][3] = 0.f;
      }
    }
  } else {
#pragma unroll
    for (int i = 0; i < 4; i++)
#pragma unroll
      for (int j = 0; j < 4; j++) {
        int n = n0 + cb + j;
        v[i][j] = (n < Csrc) ? src[(size_t)(rowBase + (kb + i) * rowStride) * Csrc + n] : 0.f;
      }
  }
#pragma unroll
  for (int j = 0; j < 4; j++) {
    uint32_t lo = (uint32_t)f2bf(v[0][j]) | ((uint32_t)f2bf(v[1][j]) << 16);
    uint32_t hi = (uint32_t)f2bf(v[2][j]) | ((uint32_t)f2bf(v[3][j]) << 16);
    *(uint2*)&T[cb + j][kb] = make_uint2(lo, hi);   // 8B aligned
  }
  __syncthreads();
#pragma unroll
  for (int i = 0; i < 2; i++) {
    int n = (t >> 3) + i * 32;
    int c8 = (t & 7) * 8;
    if (n0 + n < Cpad)
      *(uint4*)(dst + (size_t)(n0 + n) * ldk + k0 + c8) = *(const uint4*)&T[n][c8];
  }
}

// ---------------------------------------------------------------------------
// RoIAlign: block per (padded) roi, lane per channel; featT NHWC bf16.
// Output xb[roi][(py*7+px)*256 + c]; rows >= K zeroed.
// ---------------------------------------------------------------------------
__global__ __launch_bounds__(256) void roialign_kernel(
    const uint16_t* __restrict__ featT, const float* __restrict__ props,
    uint16_t* __restrict__ xb, int K)
{
  __shared__ float wy0[14], wy1[14], wx0[14], wx1[14];
  __shared__ int iy0[14], iy1[14], ix0[14], ix1[14];
  __shared__ int sb;
  int roi = blockIdx.x;
  int c = threadIdx.x;
  if (roi >= K) {
    uint16_t* xr = xb + (size_t)roi * D_FEAT + c;
    for (int s = 0; s < 49; s++) xr[s * 256] = 0;
    return;
  }
  if (threadIdx.x < 28) {
    int j = threadIdx.x % 14;
    bool isx = threadIdx.x >= 14;
    const float* p = props + roi * 5;
    float lo = (isx ? p[1] : p[2]) * 0.0625f;
    float hi = (isx ? p[3] : p[4]) * 0.0625f;
    float ext = fmaxf(hi - lo, 1.0f);
    float bin = ext * (1.0f / 7.0f);
    float y = lo + (j + 0.5f) * 0.5f * bin;
    bool valid = (y > -1.0f) && (y < 50.0f);
    float yc = fminf(fmaxf(y, 0.0f), 49.0f);
    int i0 = (int)yc;
    int i1 = min(i0 + 1, 49);
    float fhi = yc - (float)i0;
    float flo = 1.0f - fhi;
    if (!valid) { flo = 0.0f; fhi = 0.0f; }
    if (isx) { ix0[j] = i0; ix1[j] = i1; wx0[j] = flo; wx1[j] = fhi; }
    else     { iy0[j] = i0; iy1[j] = i1; wy0[j] = flo; wy1[j] = fhi; }
  }
  if (threadIdx.x == 0) sb = (int)props[roi * 5];
  __syncthreads();

  const uint16_t* fb = featT + (size_t)sb * (2500 * 256) + c;
  uint16_t* xr = xb + (size_t)roi * D_FEAT + c;
  for (int py = 0; py < 7; py++) {
    for (int px = 0; px < 7; px++) {
      float acc = 0.f;
#pragma unroll
      for (int sy = 0; sy < 2; sy++) {
        int jy = py * 2 + sy;
        int y0 = iy0[jy], y1 = iy1[jy];
        float a0 = wy0[jy], a1 = wy1[jy];
#pragma unroll
        for (int sx = 0; sx < 2; sx++) {
          int jx = px * 2 + sx;
          int x0 = ix0[jx], x1 = ix1[jx];
          float b0 = wx0[jx], b1 = wx1[jx];
          float v00 = bf2f(fb[(y0 * 50 + x0) * 256]);
          float v01 = bf2f(fb[(y0 * 50 + x1) * 256]);
          float v10 = bf2f(fb[(y1 * 50 + x0) * 256]);
          float v11 = bf2f(fb[(y1 * 50 + x1) * 256]);
          acc += a0 * (b0 * v00 + b1 * v01) + a1 * (b0 * v10 + b1 * v11);
        }
      }
      xr[(py * 7 + px) * 256] = f2bf(acc * 0.25f);
    }
  }
}

// ---------------------------------------------------------------------------
// GEMM core: 128x128 C-tile, BK=32, 4 waves; global_load_lds width-16 with
// XOR-swizzled LDS so frag ds_read_b128 is conflict-free-ish.
// ---------------------------------------------------------------------------
__device__ __forceinline__ void gemm_core(
    const uint16_t* __restrict__ A, int lda,
    const uint16_t* __restrict__ BT, int ldb,
    int Mbase, int Nbase, int kStart, int kSteps,
    uint16_t* As, uint16_t* Bs, float4v acc[4][4])
{
  const int t = threadIdx.x;
  const int w = t >> 6, L = t & 63;
  const int wm = (w & 1) * 64, wn = (w >> 1) * 64;

  const int kg = (L & 3) ^ ((L >> 3) & 3);   // XOR swizzle on k-group
  const int rsub = L >> 2;
  const uint16_t* aG0 = A + (size_t)(Mbase + 32 * w + rsub) * lda + kStart + kg * 8;
  const uint16_t* aG1 = aG0 + (size_t)16 * lda;
  const uint16_t* bG0 = BT + (size_t)(Nbase + 32 * w + rsub) * ldb + kStart + kg * 8;
  const uint16_t* bG1 = bG0 + (size_t)16 * ldb;
  uint16_t* aL0 = As + (2 * w) * 512;  uint16_t* aL1 = aL0 + 512;
  uint16_t* bL0 = Bs + (2 * w) * 512;  uint16_t* bL1 = bL0 + 512;

  const int q = L >> 4, lr = L & 15;
  const int slot = q ^ ((L >> 1) & 3);
  const uint16_t* aF = As + (wm + lr) * 32 + slot * 8;
  const uint16_t* bF = Bs + (wn + lr) * 32 + slot * 8;

  for (int ks = 0; ks < kSteps; ks++) {
    __syncthreads();
    gll16(aG0, aL0); gll16(aG1, aL1);
    gll16(bG0, bL0); gll16(bG1, bL1);
    __syncthreads();

    short8 a0 = *(const short8*)(aF);
    short8 a1 = *(const short8*)(aF + 512);
    short8 a2 = *(const short8*)(aF + 1024);
    short8 a3 = *(const short8*)(aF + 1536);
    short8 b0 = *(const short8*)(bF);
    short8 b1 = *(const short8*)(bF + 512);
    short8 b2 = *(const short8*)(bF + 1024);
    short8 b3 = *(const short8*)(bF + 1536);

    acc[0][0] = __builtin_amdgcn_mfma_f32_16x16x32_bf16(a0, b0, acc[0][0], 0, 0, 0);
    acc[0][1] = __builtin_amdgcn_mfma_f32_16x16x32_bf16(a0, b1, acc[0][1], 0, 0, 0);
    acc[0][2] = __builtin_amdgcn_mfma_f32_16x16x32_bf16(a0, b2, acc[0][2], 0, 0, 0);
    acc[0][3] = __builtin_amdgcn_mfma_f32_16x16x32_bf16(a0, b3, acc[0][3], 0, 0, 0);
    acc[1][0] = __builtin_amdgcn_mfma_f32_16x16x32_bf16(a1, b0, acc[1][0], 0, 0, 0);
    acc[1][1] = __builtin_amdgcn_mfma_f32_16x16x32_bf16(a1, b1, acc[1][1], 0, 0, 0);
    acc[1][2] = __builtin_amdgcn_mfma_f32_16x16x32_bf16(a1, b2, acc[1][2], 0, 0, 0);
    acc[1][3] = __builtin_amdgcn_mfma_f32_16x16x32_bf16(a1, b3, acc[1][3], 0, 0, 0);
    acc[2][0] = __builtin_amdgcn_mfma_f32_16x16x32_bf16(a2, b0, acc[2][0], 0, 0, 0);
    acc[2][1] = __builtin_amdgcn_mfma_f32_16x16x32_bf16(a2, b1, acc[2][1], 0, 0, 0);
    acc[2][2] = __builtin_amdgcn_mfma_f32_16x16x32_bf16(a2, b2, acc[2][2], 0, 0, 0);
    acc[2][3] = __builtin_amdgcn_mfma_f32_16x16x32_bf16(a2, b3, acc[2][3], 0, 0, 0);
    acc[3][0] = __builtin_amdgcn_mfma_f32_16x16x32_bf16(a3, b0, acc[3][0], 0, 0, 0);
    acc[3][1] = __builtin_amdgcn_mfma_f32_16x16x32_bf16(a3, b1, acc[3][1], 0, 0, 0);
    acc[3][2] = __builtin_amdgcn_mfma_f32_16x16x32_bf16(a3, b2, acc[3][2], 0, 0, 0);
    acc[3][3] = __builtin_amdgcn_mfma_f32_16x16x32_bf16(a3, b3, acc[3][3], 0, 0, 0);

    aG0 += 32; aG1 += 32; bG0 += 32; bG1 += 32;
  }
}

__device__ __forceinline__ void store_partial(
    float4v acc[4][4], float* Pz, int ldc, int Mbase, int Nbase)
{
  const int t = threadIdx.x, w = t >> 6, L = t & 63;
  const int wm = (w & 1) * 64, wn = (w >> 1) * 64, q = L >> 4, lr = L & 15;
#pragma unroll
  for (int mi = 0; mi < 4; mi++)
#pragma unroll
    for (int ni = 0; ni < 4; ni++) {
      int row = Mbase + wm + mi * 16 + q * 4;
      int col = Nbase + wn + ni * 16 + lr;
      float* pp = Pz + (size_t)row * ldc + col;
      pp[0] = acc[mi][ni][0];
      pp[ldc] = acc[mi][ni][1];
      pp[2 * ldc] = acc[mi][ni][2];
      pp[3 * ldc] = acc[mi][ni][3];
    }
}

// gemm1: 1D grid, L = x*(16<<ZBITS) + y*(1<<ZBITS) + z  ->  L % 8 keys XCD.
template<int ZBITS, int ZMASK>
__global__ __launch_bounds__(256) void gemm1_kernel(
    const uint16_t* __restrict__ A, const uint16_t* __restrict__ BT,
    int kChunk, float* __restrict__ P)
{
  __shared__ __align__(16) uint16_t As[4096];
  __shared__ __align__(16) uint16_t Bs[4096];
  float4v acc[4][4];
  float4v zero = {0.f, 0.f, 0.f, 0.f};
#pragma unroll
  for (int i = 0; i < 4; i++)
#pragma unroll
    for (int j = 0; j < 4; j++) acc[i][j] = zero;

  int Lb = blockIdx.x;
  int z = Lb & ZMASK, y = (Lb >> ZBITS) & 15, x = Lb >> (ZBITS + 4);
  gemm_core(A, D_FEAT, BT, D_FEAT, x * 128, y * 128, z * kChunk, kChunk >> 5,
            As, Bs, acc);
  store_partial(acc, P + (size_t)z * (1024 * 2048), 2048, x * 128, y * 128);
}

// generic 3D split-K partial GEMM (used for gemm2)
__global__ __launch_bounds__(256) void gemm_partial_kernel(
    const uint16_t* __restrict__ A, int lda,
    const uint16_t* __restrict__ BT, int ldb,
    int kChunk, float* __restrict__ P, int ldc, size_t zstride)
{
  __shared__ __align__(16) uint16_t As[4096];
  __shared__ __align__(16) uint16_t Bs[4096];
  float4v acc[4][4];
  float4v zero = {0.f, 0.f, 0.f, 0.f};
#pragma unroll
  for (int i = 0; i < 4; i++)
#pragma unroll
    for (int j = 0; j < 4; j++) acc[i][j] = zero;

  gemm_core(A, lda, BT, ldb, blockIdx.x * 128, blockIdx.y * 128,
            blockIdx.z * kChunk, kChunk >> 5, As, Bs, acc);
  store_partial(acc, P + (size_t)blockIdx.z * zstride, ldc,
                blockIdx.x * 128, blockIdx.y * 128);
}

// sum split-K partials + bias + relu -> bf16
__global__ void reduce_kernel(
    const float* __restrict__ P, int nsplit, size_t zstride,
    const float* __restrict__ biasLo, const float* __restrict__ biasHi,
    int colSplit, int ldrow, uint16_t* __restrict__ out, int total4)
{
  int tid = blockIdx.x * blockDim.x + threadIdx.x;
  if (tid >= total4) return;
  size_t i4 = (size_t)tid * 4;
  int col = (int)(i4 % (size_t)ldrow);
  float4 s = *(const float4*)(P + i4);
  for (int z = 1; z < nsplit; z++) {
    float4 p = *(const float4*)(P + (size_t)z * zstride + i4);
    s.x += p.x; s.y += p.y; s.z += p.z; s.w += p.w;
  }
  const float* bp = (col < colSplit) ? (biasLo + col) : (biasHi + (col - colSplit));
  s.x = fmaxf(s.x + bp[0], 0.f);
  s.y = fmaxf(s.y + bp[1], 0.f);
  s.z = fmaxf(s.z + bp[2], 0.f);
  s.w = fmaxf(s.w + bp[3], 0.f);
  uint32_t lo = (uint32_t)f2bf(s.x) | ((uint32_t)f2bf(s.y) << 16);
  uint32_t hi = (uint32_t)f2bf(s.z) | ((uint32_t)f2bf(s.w) << 16);
  *(uint2*)(out + i4) = make_uint2(lo, hi);
}

// final layer partials: grid (8, 2 heads, 4 z); P layout [z][1024][256]
__global__ __launch_bounds__(256) void gemm_final_kernel(
    const uint16_t* __restrict__ hb2, const uint16_t* __restrict__ cc,
    const uint16_t* __restrict__ w3t, const uint16_t* __restrict__ wc2t,
    float* __restrict__ P)
{
  __shared__ __align__(16) uint16_t As[4096];
  __shared__ __align__(16) uint16_t Bs[4096];
  float4v acc[4][4];
  float4v zero = {0.f, 0.f, 0.f, 0.f};
#pragma unroll
  for (int i = 0; i < 4; i++)
#pragma unroll
    for (int j = 0; j < 4; j++) acc[i][j] = zero;

  int head = blockIdx.y, z = blockIdx.z;
  const uint16_t* A = head ? cc : hb2;
  int lda = head ? 2048 : 1024;
  const uint16_t* BT = head ? wc2t : w3t;

  gemm_core(A, lda, BT, 1024, blockIdx.x * 128, 0, z * 256, 8, As, Bs, acc);
  store_partial(acc, P + (size_t)z * (1024 * 256), 256, blockIdx.x * 128, head * 128);
}

// sum final partials + bias -> d_out (bbox then logits, flat)
__global__ void reduce3_kernel(
    const float* __restrict__ P, const float* __restrict__ b3,
    const float* __restrict__ bc2, float* __restrict__ out, int K)
{
  int tid = blockIdx.x * blockDim.x + threadIdx.x;
  if (tid >= K * 85) return;
  int row = tid / 85, c = tid - row * 85;
  int head = (c >= 4);
  int col = head ? (c - 4) : c;
  int pc = head * 128 + col;
  float s = 0.f;
#pragma unroll
  for (int z = 0; z < 4; z++) s += P[(size_t)z * (1024 * 256) + row * 256 + pc];
  s += head ? bc2[col] : b3[col];
  if (head) out[4000 + row * 81 + col] = s;
  else      out[row * 4 + col] = s;
}

// ---------------------------------------------------------------------------
extern "C" void kernel_launch(void* const* d_in, const int* in_sizes, int n_in,
                              void* d_out, int out_size, void* d_ws, size_t ws_size,
                              hipStream_t stream)
{
  const float* features = (const float*)d_in[0];
  const float* props    = (const float*)d_in[1];
  const float* W1  = (const float*)d_in[2];
  const float* b1  = (const float*)d_in[3];
  const float* W2  = (const float*)d_in[4];
  const float* b2  = (const float*)d_in[5];
  const float* W3  = (const float*)d_in[6];
  const float* b3  = (const float*)d_in[7];
  const float* Wc1 = (const float*)d_in[8];
  const float* bc1 = (const float*)d_in[9];
  const float* Wc2 = (const float*)d_in[10];
  const float* bc2 = (const float*)d_in[11];
  int K = in_sizes[1] / 5;   // 1000

  char* ws = (char*)d_ws;
  size_t off = 0;
  auto take = [&](size_t bytes) { size_t o = off; off = (off + bytes + 255) & ~(size_t)255; return o; };
  uint16_t* featT = (uint16_t*)(ws + take((size_t)2 * 2500 * 256 * 2));
  uint16_t* xb    = (uint16_t*)(ws + take((size_t)MPAD * D_FEAT * 2));
  uint16_t* w1t   = (uint16_t*)(ws + take((size_t)2048 * D_FEAT * 2));
  uint16_t* w2t   = (uint16_t*)(ws + take((size_t)1024 * 1024 * 2));
  uint16_t* w3t   = (uint16_t*)(ws + take((size_t)128 * 1024 * 2));
  uint16_t* wc2t  = (uint16_t*)(ws + take((size_t)128 * 1024 * 2));
  uint16_t* hbcc  = (uint16_t*)(ws + take((size_t)1024 * 2048 * 2));
  uint16_t* hb2   = (uint16_t*)(ws + take((size_t)1024 * 1024 * 2));
  size_t pOff = off;
  float* P = (float*)(ws + pOff);
  // split-K for gemm1: 8 if partials fit, else 4
  size_t need8 = pOff + (size_t)8 * 1024 * 2048 * 4;
  int z1 = (ws_size >= need8) ? 8 : 4;

  prep_kernel<<<6912, 256, 0, stream>>>(features, W1, Wc1, W2, W3, Wc2,
                                        featT, w1t, w2t, w3t, wc2t);
  roialign_kernel<<<MPAD, 256, 0, stream>>>(featT, props, xb, K);

  // gemm1: M=1024 N=2048 K=12544, XCD-swizzled 1D grid
  if (z1 == 8)
    gemm1_kernel<3, 7><<<1024, 256, 0, stream>>>(xb, w1t, D_FEAT / 8, P);
  else
    gemm1_kernel<2, 3><<<512, 256, 0, stream>>>(xb, w1t, D_FEAT / 4, P);
  reduce_kernel<<<2048, 256, 0, stream>>>(P, z1, (size_t)1024 * 2048,
                                          b1, bc1, 1024, 2048, hbcc, 524288);
  // gemm2: h @ W2, M=1024 N=1024 K=1024, split-K=8
  gemm_partial_kernel<<<dim3(8, 8, 8), 256, 0, stream>>>(
      hbcc, 2048, w2t, 1024, 128, P, 1024, (size_t)1024 * 1024);
  reduce_kernel<<<1024, 256, 0, stream>>>(P, 8, (size_t)1024 * 1024,
                                          b2, b2, 1024, 1024, hb2, 262144);
  // final: bbox (hb2@W3) / logits (cc@Wc2), split-K=4 partials
  gemm_final_kernel<<<dim3(8, 2, 4), 256, 0, stream>>>(hb2, hbcc + 1024, w3t, wc2t, P);
  reduce3_kernel<<<(K * 85 + 255) / 256, 256, 0, stream>>>(P, b3, bc2, (float*)d_out, K);
}